// Round 1
// baseline (557.174 us; speedup 1.0000x reference)
//
#include <hip/hip_runtime.h>
#include <stdint.h>

// ---------------- problem constants ----------------
#define BB 8
#define CC 3
#define HH 128
#define DD 2048
#define FF 8192
#define NCLS 1000
#define MTOK (BB*CC*HH)          // 3072 tokens
#define NW   (FF*DD)             // 16777216 weight elements per matrix
#define INV_NW (1.0f/16777216.0f)

typedef __attribute__((ext_vector_type(4))) int i32x4;

// ---------------- workspace layout (bytes) ----------------
// [0)      sums[4]      : sum|Wg|, sum|Wu|, sum|Wd|
// [256)    pooled[24]   : B*C accumulators
// [1024)   tsum[8192]   : colsum of ternary Wd (float, integer-valued)
// [33792)  inv_sa[3072] : clip(max|x_row|,1e-5)/127
// [46080)  xq  int8 [3072][2048]
// [6337536)  wgq int8 [8192][2048]
// [23114752) wuq int8 [8192][2048]
// [39891968) h fp32 [3072][8192]
#define WS_SUMS    0
#define WS_POOLED  256
#define WS_TSUM    1024
#define WS_INVSA   33792
#define WS_XQ      46080
#define WS_WGQ     6337536
#define WS_WUQ     23114752
#define WS_H       39891968
#define WS_NEED    140555264
#define WS_ZERO_BYTES 33792      // sums + pooled + tsum

// ---------------- K1a: abs-sum reduce (one weight matrix -> one slot) ----------------
__global__ __launch_bounds__(256) void abssum_kernel(const float* __restrict__ w,
                                                     float* __restrict__ slot) {
  size_t i = ((size_t)blockIdx.x * 256 + threadIdx.x) * 4;
  const size_t stride = (size_t)gridDim.x * 256 * 4;
  float s = 0.f;
  for (; i < (size_t)NW; i += stride) {
    float4 v = *(const float4*)(w + i);
    s += fabsf(v.x) + fabsf(v.y) + fabsf(v.z) + fabsf(v.w);
  }
  for (int off = 32; off > 0; off >>= 1) s += __shfl_xor(s, off);
  __shared__ float wsum[4];
  int wave = threadIdx.x >> 6, lane = threadIdx.x & 63;
  if (lane == 0) wsum[wave] = s;
  __syncthreads();
  if (threadIdx.x == 0) atomicAdd(slot, (wsum[0] + wsum[1]) + (wsum[2] + wsum[3]));
}

// ---------------- K1b: per-token absmax + int8 quantize of x ----------------
__global__ __launch_bounds__(256) void quant_x_kernel(const float* __restrict__ x,
                                                      int8_t* __restrict__ xq,
                                                      float* __restrict__ inv_sa) {
  const int tok = blockIdx.x, t = threadIdx.x;
  const float* row = x + (size_t)tok * DD;
  float4 v0 = *(const float4*)(row + t * 4);
  float4 v1 = *(const float4*)(row + 1024 + t * 4);
  float mx = fmaxf(fmaxf(fmaxf(fabsf(v0.x), fabsf(v0.y)), fmaxf(fabsf(v0.z), fabsf(v0.w))),
                   fmaxf(fmaxf(fabsf(v1.x), fabsf(v1.y)), fmaxf(fabsf(v1.z), fabsf(v1.w))));
  for (int off = 32; off > 0; off >>= 1) mx = fmaxf(mx, __shfl_xor(mx, off));
  __shared__ float wm[4];
  int wave = t >> 6, lane = t & 63;
  if (lane == 0) wm[wave] = mx;
  __syncthreads();
  float m = fmaxf(fmaxf(wm[0], wm[1]), fmaxf(wm[2], wm[3]));
  float mclip = fmaxf(m, 1e-5f);
  float sa = 127.0f / mclip;
  if (t == 0) inv_sa[tok] = mclip * (1.0f / 127.0f);
  // quantize 8 values, pack 4 bytes per store
  float q[8] = {v0.x, v0.y, v0.z, v0.w, v1.x, v1.y, v1.z, v1.w};
  unsigned p0 = 0, p1 = 0;
#pragma unroll
  for (int j = 0; j < 4; ++j) {
    int qi = (int)fminf(fmaxf(rintf(q[j] * sa), -128.f), 127.f);
    p0 |= ((unsigned)(qi & 0xff)) << (8 * j);
  }
#pragma unroll
  for (int j = 0; j < 4; ++j) {
    int qi = (int)fminf(fmaxf(rintf(q[4 + j] * sa), -128.f), 127.f);
    p1 |= ((unsigned)(qi & 0xff)) << (8 * j);
  }
  *(unsigned*)(xq + (size_t)tok * DD + t * 4) = p0;
  *(unsigned*)(xq + (size_t)tok * DD + 1024 + t * 4) = p1;
}

// ---------------- K1c: ternarize a weight matrix to int8 ----------------
__global__ __launch_bounds__(256) void quant_w_kernel(const float* __restrict__ w,
                                                      int8_t* __restrict__ wq,
                                                      const float* __restrict__ sums, int slot) {
  const float scale = 1.0f / fmaxf(sums[slot] * INV_NW, 1e-5f);
  size_t i = ((size_t)blockIdx.x * 256 + threadIdx.x) * 4;
  float4 v = *(const float4*)(w + i);
  unsigned p = 0;
  float vv[4] = {v.x, v.y, v.z, v.w};
#pragma unroll
  for (int j = 0; j < 4; ++j) {
    int qi = (int)fminf(fmaxf(rintf(vv[j] * scale), -1.f), 1.f);
    p |= ((unsigned)(qi & 0xff)) << (8 * j);
  }
  *(unsigned*)(wq + i) = p;
}

// ---------------- K1d: column-sum of ternary Wd -> tsum[FF] ----------------
__global__ __launch_bounds__(256) void wd_colsum_kernel(const float* __restrict__ wd,
                                                        const float* __restrict__ sums,
                                                        float* __restrict__ tsum) {
  const float scale = 1.0f / fmaxf(sums[2] * INV_NW, 1e-5f);
  const int k = blockIdx.x * 256 + threadIdx.x;   // 0..8191
  float acc = 0.f;
  const int d0 = blockIdx.y * 128;
  for (int d = d0; d < d0 + 128; ++d) {
    float w = wd[(size_t)d * FF + k];
    acc += fminf(fmaxf(rintf(w * scale), -1.f), 1.f);
  }
  atomicAdd(&tsum[k], acc);
}

// ---------------- K2: fused int8-MFMA GEMM (g and u) + silu*u epilogue ----------------
__device__ __forceinline__ void gl_lds16(const void* g, void* l) {
  __builtin_amdgcn_global_load_lds((const __attribute__((address_space(1))) void*)g,
                                   (__attribute__((address_space(3))) void*)l, 16, 0, 0);
}

__global__ __launch_bounds__(256, 2) void gemm_gu_kernel(
    const int8_t* __restrict__ Aq,    // [3072][2048]
    const int8_t* __restrict__ Bgq,   // [8192][2048]
    const int8_t* __restrict__ Buq,   // [8192][2048]
    const float* __restrict__ inv_sa, // [3072]
    const float* __restrict__ sums,
    float* __restrict__ Hbuf)         // [3072][8192]
{
  __shared__ int8_t ldsA[128 * 64];   // 8 KB each, rows of 64 B (4 chunks of 16B)
  __shared__ int8_t ldsG[128 * 64];
  __shared__ int8_t ldsU[128 * 64];

  const int t = threadIdx.x;
  const int wave = t >> 6, lane = t & 63;
  const int q = lane >> 4, ln = lane & 15;
  const int m0 = blockIdx.x * 128;    // token tile
  const int n0 = blockIdx.y * 128;    // F tile
  const int wm = (wave >> 1) * 64, wn = (wave & 1) * 64;

  i32x4 accg[4][4], accu[4][4];
#pragma unroll
  for (int i = 0; i < 4; ++i)
#pragma unroll
    for (int j = 0; j < 4; ++j) { accg[i][j] = i32x4{0,0,0,0}; accu[i][j] = i32x4{0,0,0,0}; }

  const int srow = lane >> 2;  // 0..15: row within a 16-row staging call
  const int sp = lane & 3;     // chunk position 0..3

  for (int k0 = 0; k0 < DD; k0 += 64) {
    __syncthreads();
    // stage: each wave fills 32 rows of each tile, 2 calls x 16 rows, 16B/lane
#pragma unroll
    for (int j = 0; j < 2; ++j) {
      const int rl = wave * 32 + j * 16 + srow;
      const int cg = sp ^ (rl & 3) ^ ((rl >> 2) & 3);   // XOR swizzle (conflict-free b128 reads)
      const size_t ga = (size_t)(m0 + rl) * DD + k0 + cg * 16;
      const size_t gb = (size_t)(n0 + rl) * DD + k0 + cg * 16;
      int8_t* ldst = (int8_t*)((wave * 32 + j * 16) * 64);
      gl_lds16(Aq + ga, ldsA + (wave * 32 + j * 16) * 64);
      gl_lds16(Bgq + gb, ldsG + (wave * 32 + j * 16) * 64);
      gl_lds16(Buq + gb, ldsU + (wave * 32 + j * 16) * 64);
      (void)ldst;
    }
    __syncthreads();

    i32x4 af[4], gf[4], uf[4];
#pragma unroll
    for (int mt = 0; mt < 4; ++mt) {
      const int row = wm + mt * 16 + ln;
      const int p = q ^ (row & 3) ^ ((row >> 2) & 3);
      af[mt] = *(const i32x4*)(ldsA + row * 64 + p * 16);
    }
#pragma unroll
    for (int nt = 0; nt < 4; ++nt) {
      const int row = wn + nt * 16 + ln;
      const int p = q ^ (row & 3) ^ ((row >> 2) & 3);
      gf[nt] = *(const i32x4*)(ldsG + row * 64 + p * 16);
      uf[nt] = *(const i32x4*)(ldsU + row * 64 + p * 16);
    }
#pragma unroll
    for (int mt = 0; mt < 4; ++mt)
#pragma unroll
      for (int nt = 0; nt < 4; ++nt) {
        accg[mt][nt] = __builtin_amdgcn_mfma_i32_16x16x64_i8(af[mt], gf[nt], accg[mt][nt], 0, 0, 0);
        accu[mt][nt] = __builtin_amdgcn_mfma_i32_16x16x64_i8(af[mt], uf[nt], accu[mt][nt], 0, 0, 0);
      }
  }

  // epilogue: g = acc * (1/sa) * (1/scale_w);  note 1/scale_w = clip(mean|W|,1e-5)
  const float meanWg = fmaxf(sums[0] * INV_NW, 1e-5f);
  const float meanWu = fmaxf(sums[1] * INV_NW, 1e-5f);
#pragma unroll
  for (int mt = 0; mt < 4; ++mt) {
#pragma unroll
    for (int r = 0; r < 4; ++r) {
      const int row = m0 + wm + mt * 16 + q * 4 + r;   // C/D layout: row = quad*4+reg
      const float isa = inv_sa[row];
      const float sg = isa * meanWg, su = isa * meanWu;
      float* hrow = Hbuf + (size_t)row * FF + n0 + wn;
#pragma unroll
      for (int nt = 0; nt < 4; ++nt) {
        const float g = (float)accg[mt][nt][r] * sg;
        const float u = (float)accu[mt][nt][r] * su;
        const float s = g / (1.0f + expf(-g));         // silu
        hrow[nt * 16 + ln] = s * u;                    // col = lane&15
      }
    }
  }
}

// ---------------- K4: rmsnorm stats + requant + dot(tsum) per token ----------------
__global__ __launch_bounds__(256) void rms_quant_dot_kernel(
    const float* __restrict__ H, const float* __restrict__ lnw,
    const float* __restrict__ tsum, float* __restrict__ pooled) {
  const int tok = blockIdx.x, t = threadIdx.x;
  const float* row = H + (size_t)tok * FF;
  float4 hv[8];
  float ssq = 0.f, mx = 0.f;
#pragma unroll
  for (int i = 0; i < 8; ++i) {
    hv[i] = *(const float4*)(row + i * 1024 + t * 4);
    float4 lw = *(const float4*)(lnw + i * 1024 + t * 4);
    ssq += hv[i].x * hv[i].x + hv[i].y * hv[i].y + hv[i].z * hv[i].z + hv[i].w * hv[i].w;
    mx = fmaxf(mx, fmaxf(fmaxf(fabsf(hv[i].x * lw.x), fabsf(hv[i].y * lw.y)),
                         fmaxf(fabsf(hv[i].z * lw.z), fabsf(hv[i].w * lw.w))));
  }
  for (int off = 32; off > 0; off >>= 1) {
    ssq += __shfl_xor(ssq, off);
    mx = fmaxf(mx, __shfl_xor(mx, off));
  }
  __shared__ float rs[4], rm[4], ra[4];
  const int wave = t >> 6, lane = t & 63;
  if (lane == 0) { rs[wave] = ssq; rm[wave] = mx; }
  __syncthreads();
  const float S = (rs[0] + rs[1]) + (rs[2] + rs[3]);
  const float M = fmaxf(fmaxf(rm[0], rm[1]), fmaxf(rm[2], rm[3]));
  const float r = rsqrtf(S * (1.0f / (float)FF) + 1e-6f);
  const float mc = fmaxf(M * r, 1e-5f);     // clip(max|y|, Q_EPS)
  const float as2 = 127.0f / mc;
  float acc = 0.f;
#pragma unroll
  for (int i = 0; i < 8; ++i) {
    float4 lw = *(const float4*)(lnw + i * 1024 + t * 4);
    float4 ts = *(const float4*)(tsum + i * 1024 + t * 4);
    float y0 = hv[i].x * lw.x * r, y1 = hv[i].y * lw.y * r;
    float y2 = hv[i].z * lw.z * r, y3 = hv[i].w * lw.w * r;
    acc += fminf(fmaxf(rintf(y0 * as2), -128.f), 127.f) * ts.x;
    acc += fminf(fmaxf(rintf(y1 * as2), -128.f), 127.f) * ts.y;
    acc += fminf(fmaxf(rintf(y2 * as2), -128.f), 127.f) * ts.z;
    acc += fminf(fmaxf(rintf(y3 * as2), -128.f), 127.f) * ts.w;
  }
  for (int off = 32; off > 0; off >>= 1) acc += __shfl_xor(acc, off);
  if (lane == 0) ra[wave] = acc;
  __syncthreads();
  if (t == 0)
    atomicAdd(&pooled[tok >> 7], ((ra[0] + ra[1]) + (ra[2] + ra[3])) * (mc * (1.0f / 127.0f)));
}

// ---------------- K5: classifier ----------------
__global__ __launch_bounds__(256) void classifier_kernel(
    const float* __restrict__ pooled, const float* __restrict__ sums,
    const float* __restrict__ clsW, const float* __restrict__ clsb,
    float* __restrict__ out) {
  const int b = blockIdx.x;
  const float meanWd = fmaxf(sums[2] * INV_NW, 1e-5f);
  const float sc = meanWd * (1.0f / (float)(HH * DD));
  const float p0 = pooled[b * 3 + 0] * sc;
  const float p1 = pooled[b * 3 + 1] * sc;
  const float p2 = pooled[b * 3 + 2] * sc;
  for (int n = threadIdx.x; n < NCLS; n += 256)
    out[b * NCLS + n] = clsb[n] + p0 * clsW[n * 3 + 0] + p1 * clsW[n * 3 + 1] + p2 * clsW[n * 3 + 2];
}

// ---------------- launch ----------------
extern "C" void kernel_launch(void* const* d_in, const int* in_sizes, int n_in,
                              void* d_out, int out_size, void* d_ws, size_t ws_size,
                              hipStream_t stream) {
  if (n_in < 7 || ws_size < (size_t)WS_NEED) return;
  const float* x = (const float*)d_in[0];
  const float* Wg = (const float*)d_in[1];
  const float* Wu = (const float*)d_in[2];
  const float* Wd = (const float*)d_in[3];
  const float* lnw = (const float*)d_in[4];
  const float* clsW = (const float*)d_in[5];
  const float* clsb = (const float*)d_in[6];
  float* out = (float*)d_out;
  char* ws = (char*)d_ws;
  float* sums = (float*)(ws + WS_SUMS);
  float* pooled = (float*)(ws + WS_POOLED);
  float* tsum = (float*)(ws + WS_TSUM);
  float* inv_sa = (float*)(ws + WS_INVSA);
  int8_t* xq = (int8_t*)(ws + WS_XQ);
  int8_t* wgq = (int8_t*)(ws + WS_WGQ);
  int8_t* wuq = (int8_t*)(ws + WS_WUQ);
  float* hbuf = (float*)(ws + WS_H);

  hipMemsetAsync(ws, 0, WS_ZERO_BYTES, stream);
  abssum_kernel<<<4096, 256, 0, stream>>>(Wg, &sums[0]);
  abssum_kernel<<<4096, 256, 0, stream>>>(Wu, &sums[1]);
  abssum_kernel<<<4096, 256, 0, stream>>>(Wd, &sums[2]);
  quant_x_kernel<<<MTOK, 256, 0, stream>>>(x, xq, inv_sa);
  quant_w_kernel<<<16384, 256, 0, stream>>>(Wg, wgq, sums, 0);
  quant_w_kernel<<<16384, 256, 0, stream>>>(Wu, wuq, sums, 1);
  wd_colsum_kernel<<<dim3(32, 16), 256, 0, stream>>>(Wd, sums, tsum);
  gemm_gu_kernel<<<dim3(24, 64), 256, 0, stream>>>(xq, wgq, wuq, inv_sa, sums, hbuf);
  rms_quant_dot_kernel<<<MTOK, 256, 0, stream>>>(hbuf, lnw, tsum, pooled);
  classifier_kernel<<<BB, 256, 0, stream>>>(pooled, sums, clsW, clsb, out);
  (void)in_sizes; (void)out_size;
}

// Round 2
// 505.158 us; speedup vs baseline: 1.1030x; 1.1030x over previous
//
#include <hip/hip_runtime.h>
#include <stdint.h>

// ---------------- problem constants ----------------
#define BB 8
#define CC 3
#define HH 128
#define DD 2048
#define FF 8192
#define NCLS 1000
#define MTOK (BB*CC*HH)          // 3072 tokens
#define NW   (FF*DD)             // 16777216 weight elements per matrix
#define INV_NW (1.0f/16777216.0f)

typedef __attribute__((ext_vector_type(4))) int i32x4;
typedef _Float16 f16x8 __attribute__((ext_vector_type(8)));

// ---------------- workspace layout (bytes) ----------------
#define WS_SUMS    0            // 3 floats
#define WS_POOLED  256          // 24 floats
#define WS_TSUM    1024         // 8192 floats
#define WS_INVSA   33792        // 3072 floats
#define WS_XQ      46080        // int8 [3072][2048]
#define WS_WGQ     6337536      // int8 [8192][2048]
#define WS_WUQ     23114752     // int8 [8192][2048]
#define WS_H       39891968     // fp16 [3072][8192]
#define WS_NEED    90223616
#define WS_ZERO_BYTES 33792     // sums + pooled + tsum

// ---------------- K1: abs-sum reduce for all 3 weight matrices ----------------
__global__ __launch_bounds__(256) void abssum3_kernel(const float* __restrict__ Wg,
                                                      const float* __restrict__ Wu,
                                                      const float* __restrict__ Wd,
                                                      float* __restrict__ sums) {
  const float* w = (blockIdx.y == 0) ? Wg : (blockIdx.y == 1) ? Wu : Wd;
  size_t i = ((size_t)blockIdx.x * 256 + threadIdx.x) * 4;
  const size_t stride = (size_t)gridDim.x * 256 * 4;
  float s = 0.f;
  for (; i < (size_t)NW; i += stride) {
    float4 v = *(const float4*)(w + i);
    s += fabsf(v.x) + fabsf(v.y) + fabsf(v.z) + fabsf(v.w);
  }
  for (int off = 32; off > 0; off >>= 1) s += __shfl_xor(s, off);
  __shared__ float wsum[4];
  int wave = threadIdx.x >> 6, lane = threadIdx.x & 63;
  if (lane == 0) wsum[wave] = s;
  __syncthreads();
  if (threadIdx.x == 0) atomicAdd(&sums[blockIdx.y], (wsum[0] + wsum[1]) + (wsum[2] + wsum[3]));
}

// ---------------- K2: per-token absmax + int8 quantize of x ----------------
__global__ __launch_bounds__(256) void quant_x_kernel(const float* __restrict__ x,
                                                      int8_t* __restrict__ xq,
                                                      float* __restrict__ inv_sa) {
  const int tok = blockIdx.x, t = threadIdx.x;
  const float* row = x + (size_t)tok * DD;
  float4 v0 = *(const float4*)(row + t * 4);
  float4 v1 = *(const float4*)(row + 1024 + t * 4);
  float mx = fmaxf(fmaxf(fmaxf(fabsf(v0.x), fabsf(v0.y)), fmaxf(fabsf(v0.z), fabsf(v0.w))),
                   fmaxf(fmaxf(fabsf(v1.x), fabsf(v1.y)), fmaxf(fabsf(v1.z), fabsf(v1.w))));
  for (int off = 32; off > 0; off >>= 1) mx = fmaxf(mx, __shfl_xor(mx, off));
  __shared__ float wm[4];
  int wave = t >> 6, lane = t & 63;
  if (lane == 0) wm[wave] = mx;
  __syncthreads();
  float m = fmaxf(fmaxf(wm[0], wm[1]), fmaxf(wm[2], wm[3]));
  float mclip = fmaxf(m, 1e-5f);
  float sa = 127.0f / mclip;
  if (t == 0) inv_sa[tok] = mclip * (1.0f / 127.0f);
  float qv[8] = {v0.x, v0.y, v0.z, v0.w, v1.x, v1.y, v1.z, v1.w};
  unsigned p0 = 0, p1 = 0;
#pragma unroll
  for (int j = 0; j < 4; ++j) {
    int qi = (int)fminf(fmaxf(rintf(qv[j] * sa), -128.f), 127.f);
    p0 |= ((unsigned)(qi & 0xff)) << (8 * j);
  }
#pragma unroll
  for (int j = 0; j < 4; ++j) {
    int qi = (int)fminf(fmaxf(rintf(qv[4 + j] * sa), -128.f), 127.f);
    p1 |= ((unsigned)(qi & 0xff)) << (8 * j);
  }
  *(unsigned*)(xq + (size_t)tok * DD + t * 4) = p0;
  *(unsigned*)(xq + (size_t)tok * DD + 1024 + t * 4) = p1;
}

// ---------------- K3: ternarize Wg and Wu (grid.y selects) ----------------
__global__ __launch_bounds__(256) void quant_gu_kernel(const float* __restrict__ Wg,
                                                       const float* __restrict__ Wu,
                                                       int8_t* __restrict__ wgq,
                                                       int8_t* __restrict__ wuq,
                                                       const float* __restrict__ sums) {
  const int mat = blockIdx.y;
  const float* w = mat ? Wu : Wg;
  int8_t* wq = mat ? wuq : wgq;
  const float scale = 1.0f / fmaxf(sums[mat] * INV_NW, 1e-5f);
  size_t i = ((size_t)blockIdx.x * 256 + threadIdx.x) * 4;
  float4 v = *(const float4*)(w + i);
  float vv[4] = {v.x, v.y, v.z, v.w};
  unsigned p = 0;
#pragma unroll
  for (int j = 0; j < 4; ++j) {
    int qi = (int)fminf(fmaxf(rintf(vv[j] * scale), -1.f), 1.f);
    p |= ((unsigned)(qi & 0xff)) << (8 * j);
  }
  *(unsigned*)(wq + i) = p;
}

// ---------------- K4: column-sum of ternary Wd -> tsum[FF] ----------------
__global__ __launch_bounds__(256) void wd_colsum_kernel(const float* __restrict__ wd,
                                                        const float* __restrict__ sums,
                                                        float* __restrict__ tsum) {
  const float scale = 1.0f / fmaxf(sums[2] * INV_NW, 1e-5f);
  const int k = blockIdx.x * 256 + threadIdx.x;   // 0..8191
  float acc = 0.f;
  const int d0 = blockIdx.y * 128;
  for (int d = d0; d < d0 + 128; ++d) {
    float w = wd[(size_t)d * FF + k];
    acc += fminf(fmaxf(rintf(w * scale), -1.f), 1.f);
  }
  atomicAdd(&tsum[k], acc);
}

// ---------------- K5: fused int8-MFMA GEMM (g and u) + silu*u -> fp16 h ----------------
// Block tile M=128, N=64, BK=128. 4 waves 2x2, wave tile 64x32.
// acc = 4x2 tiles x2 gemms = 64 AGPR; ~135 total regs -> 3 blocks/CU.
__device__ __forceinline__ void gl_lds16(const void* g, void* l) {
  __builtin_amdgcn_global_load_lds((const __attribute__((address_space(1))) void*)g,
                                   (__attribute__((address_space(3))) void*)l, 16, 0, 0);
}

__global__ __launch_bounds__(256, 3) void gemm_gu_kernel(
    const int8_t* __restrict__ Aq,    // [3072][2048]
    const int8_t* __restrict__ Bgq,   // [8192][2048]
    const int8_t* __restrict__ Buq,   // [8192][2048]
    const float* __restrict__ inv_sa, // [3072]
    const float* __restrict__ sums,
    _Float16* __restrict__ Hbuf)      // [3072][8192]
{
  __shared__ int8_t ldsA[128 * 128];  // 16 KB, rows of 128 B = 8 chunks of 16 B
  __shared__ int8_t ldsG[64 * 128];   // 8 KB
  __shared__ int8_t ldsU[64 * 128];   // 8 KB

  const int t = threadIdx.x;
  const int wave = t >> 6, lane = t & 63;
  const int q = lane >> 4, ln = lane & 15;
  const int m0 = blockIdx.x * 128;    // token tile
  const int n0 = blockIdx.y * 64;     // F tile
  const int wm = (wave >> 1) * 64, wn = (wave & 1) * 32;

  i32x4 accg[4][2], accu[4][2];
#pragma unroll
  for (int i = 0; i < 4; ++i)
#pragma unroll
    for (int j = 0; j < 2; ++j) { accg[i][j] = i32x4{0,0,0,0}; accu[i][j] = i32x4{0,0,0,0}; }

  const int srow = lane >> 3;  // 0..7: row within an 8-row staging call
  const int sp = lane & 7;     // chunk position 0..7

  for (int k0 = 0; k0 < DD; k0 += 128) {
    __syncthreads();
    // A: wave fills 32 rows over 4 calls of 8 rows (8 lanes x 16B per row)
#pragma unroll
    for (int j = 0; j < 4; ++j) {
      const int rl = wave * 32 + j * 8 + srow;
      const int cg = sp ^ (rl & 7);           // XOR swizzle over 8 chunk slots
      gl_lds16(Aq + (size_t)(m0 + rl) * DD + k0 + cg * 16,
               ldsA + (wave * 32 + j * 8) * 128);
    }
    // G/U: wave fills 16 rows each over 2 calls
#pragma unroll
    for (int j = 0; j < 2; ++j) {
      const int rl = wave * 16 + j * 8 + srow;
      const int cg = sp ^ (rl & 7);
      gl_lds16(Bgq + (size_t)(n0 + rl) * DD + k0 + cg * 16,
               ldsG + (wave * 16 + j * 8) * 128);
      gl_lds16(Buq + (size_t)(n0 + rl) * DD + k0 + cg * 16,
               ldsU + (wave * 16 + j * 8) * 128);
    }
    __syncthreads();

#pragma unroll
    for (int s = 0; s < 2; ++s) {            // two k-halves of 64 within BK=128
      i32x4 af[4], gf[2], uf[2];
#pragma unroll
      for (int mt = 0; mt < 4; ++mt) {
        const int row = wm + mt * 16 + ln;
        const int p = (s * 4 + q) ^ (row & 7);
        af[mt] = *(const i32x4*)(ldsA + row * 128 + p * 16);
      }
#pragma unroll
      for (int nt = 0; nt < 2; ++nt) {
        const int row = wn + nt * 16 + ln;
        const int p = (s * 4 + q) ^ (row & 7);
        gf[nt] = *(const i32x4*)(ldsG + row * 128 + p * 16);
        uf[nt] = *(const i32x4*)(ldsU + row * 128 + p * 16);
      }
#pragma unroll
      for (int mt = 0; mt < 4; ++mt)
#pragma unroll
        for (int nt = 0; nt < 2; ++nt) {
          accg[mt][nt] = __builtin_amdgcn_mfma_i32_16x16x64_i8(af[mt], gf[nt], accg[mt][nt], 0, 0, 0);
          accu[mt][nt] = __builtin_amdgcn_mfma_i32_16x16x64_i8(af[mt], uf[nt], accu[mt][nt], 0, 0, 0);
        }
    }
  }

  const float meanWg = fmaxf(sums[0] * INV_NW, 1e-5f);
  const float meanWu = fmaxf(sums[1] * INV_NW, 1e-5f);
#pragma unroll
  for (int mt = 0; mt < 4; ++mt) {
#pragma unroll
    for (int r = 0; r < 4; ++r) {
      const int row = m0 + wm + mt * 16 + q * 4 + r;   // C/D layout: row = quad*4+reg
      const float isa = inv_sa[row];
      const float sg = isa * meanWg, su = isa * meanWu;
      _Float16* hrow = Hbuf + (size_t)row * FF + n0 + wn;
#pragma unroll
      for (int nt = 0; nt < 2; ++nt) {
        const float g = (float)accg[mt][nt][r] * sg;
        const float u = (float)accu[mt][nt][r] * su;
        const float sv = g / (1.0f + expf(-g));        // silu
        hrow[nt * 16 + ln] = (_Float16)(sv * u);       // col = lane&15
      }
    }
  }
}

// ---------------- K6: rmsnorm stats + requant + dot(tsum) per token ----------------
__global__ __launch_bounds__(256) void rms_quant_dot_kernel(
    const _Float16* __restrict__ H, const float* __restrict__ lnw,
    const float* __restrict__ tsum, float* __restrict__ pooled) {
  const int tok = blockIdx.x, t = threadIdx.x;
  const _Float16* row = H + (size_t)tok * FF;
  f16x8 hv[4];
  float ssq = 0.f, mx = 0.f;
#pragma unroll
  for (int i = 0; i < 4; ++i) {
    hv[i] = *(const f16x8*)(row + i * 2048 + t * 8);
#pragma unroll
    for (int j = 0; j < 8; ++j) {
      float h = (float)hv[i][j];
      float lw = lnw[i * 2048 + t * 8 + j];
      ssq += h * h;
      mx = fmaxf(mx, fabsf(h * lw));
    }
  }
  for (int off = 32; off > 0; off >>= 1) {
    ssq += __shfl_xor(ssq, off);
    mx = fmaxf(mx, __shfl_xor(mx, off));
  }
  __shared__ float rs[4], rm[4], ra[4];
  const int wave = t >> 6, lane = t & 63;
  if (lane == 0) { rs[wave] = ssq; rm[wave] = mx; }
  __syncthreads();
  const float S = (rs[0] + rs[1]) + (rs[2] + rs[3]);
  const float M = fmaxf(fmaxf(rm[0], rm[1]), fmaxf(rm[2], rm[3]));
  const float r = rsqrtf(S * (1.0f / (float)FF) + 1e-6f);
  const float mc = fmaxf(M * r, 1e-5f);     // clip(max|y|, Q_EPS)
  const float as2 = 127.0f / mc;
  float acc = 0.f;
#pragma unroll
  for (int i = 0; i < 4; ++i) {
#pragma unroll
    for (int j = 0; j < 8; ++j) {
      float lw = lnw[i * 2048 + t * 8 + j];
      float ts = tsum[i * 2048 + t * 8 + j];
      float y = (float)hv[i][j] * lw * r;
      acc += fminf(fmaxf(rintf(y * as2), -128.f), 127.f) * ts;
    }
  }
  for (int off = 32; off > 0; off >>= 1) acc += __shfl_xor(acc, off);
  if (lane == 0) ra[wave] = acc;
  __syncthreads();
  if (t == 0)
    atomicAdd(&pooled[tok >> 7], ((ra[0] + ra[1]) + (ra[2] + ra[3])) * (mc * (1.0f / 127.0f)));
}

// ---------------- K7: classifier ----------------
__global__ __launch_bounds__(256) void classifier_kernel(
    const float* __restrict__ pooled, const float* __restrict__ sums,
    const float* __restrict__ clsW, const float* __restrict__ clsb,
    float* __restrict__ out) {
  const int b = blockIdx.x;
  const float meanWd = fmaxf(sums[2] * INV_NW, 1e-5f);
  const float sc = meanWd * (1.0f / (float)(HH * DD));
  const float p0 = pooled[b * 3 + 0] * sc;
  const float p1 = pooled[b * 3 + 1] * sc;
  const float p2 = pooled[b * 3 + 2] * sc;
  for (int n = threadIdx.x; n < NCLS; n += 256)
    out[b * NCLS + n] = clsb[n] + p0 * clsW[n * 3 + 0] + p1 * clsW[n * 3 + 1] + p2 * clsW[n * 3 + 2];
}

// ---------------- launch ----------------
extern "C" void kernel_launch(void* const* d_in, const int* in_sizes, int n_in,
                              void* d_out, int out_size, void* d_ws, size_t ws_size,
                              hipStream_t stream) {
  if (n_in < 7 || ws_size < (size_t)WS_NEED) return;
  const float* x = (const float*)d_in[0];
  const float* Wg = (const float*)d_in[1];
  const float* Wu = (const float*)d_in[2];
  const float* Wd = (const float*)d_in[3];
  const float* lnw = (const float*)d_in[4];
  const float* clsW = (const float*)d_in[5];
  const float* clsb = (const float*)d_in[6];
  float* out = (float*)d_out;
  char* ws = (char*)d_ws;
  float* sums = (float*)(ws + WS_SUMS);
  float* pooled = (float*)(ws + WS_POOLED);
  float* tsum = (float*)(ws + WS_TSUM);
  float* inv_sa = (float*)(ws + WS_INVSA);
  int8_t* xq = (int8_t*)(ws + WS_XQ);
  int8_t* wgq = (int8_t*)(ws + WS_WGQ);
  int8_t* wuq = (int8_t*)(ws + WS_WUQ);
  _Float16* hbuf = (_Float16*)(ws + WS_H);

  hipMemsetAsync(ws, 0, WS_ZERO_BYTES, stream);
  abssum3_kernel<<<dim3(4096, 3), 256, 0, stream>>>(Wg, Wu, Wd, sums);
  quant_x_kernel<<<MTOK, 256, 0, stream>>>(x, xq, inv_sa);
  quant_gu_kernel<<<dim3(16384, 2), 256, 0, stream>>>(Wg, Wu, wgq, wuq, sums);
  wd_colsum_kernel<<<dim3(32, 16), 256, 0, stream>>>(Wd, sums, tsum);
  gemm_gu_kernel<<<dim3(24, 128), 256, 0, stream>>>(xq, wgq, wuq, inv_sa, sums, hbuf);
  rms_quant_dot_kernel<<<MTOK, 256, 0, stream>>>(hbuf, lnw, tsum, pooled);
  classifier_kernel<<<BB, 256, 0, stream>>>(pooled, sums, clsW, clsb, out);
  (void)in_sizes; (void)out_size;
}

// Round 3
// 387.176 us; speedup vs baseline: 1.4391x; 1.3047x over previous
//
#include <hip/hip_runtime.h>
#include <stdint.h>

// ---------------- problem constants ----------------
#define BB 8
#define CC 3
#define HH 128
#define DD 2048
#define FF 8192
#define NCLS 1000
#define MTOK (BB*CC*HH)          // 3072 tokens
#define NW   (FF*DD)             // 16777216 weight elements per matrix
#define INV_NW (1.0f/16777216.0f)

typedef __attribute__((ext_vector_type(4))) int i32x4;
typedef _Float16 f16x8 __attribute__((ext_vector_type(8)));

// ---------------- workspace layout (bytes) ----------------
// sums: 3 slots at float index 0 / 64 / 128 (padded to separate cachelines)
#define WS_SUMS    0
#define WS_POOLED  1024         // 3072 floats (one per token, no atomics)
#define WS_TSUM    16384        // 8192 floats
#define WS_INVSA   49152        // 3072 floats
#define WS_XQ      61440        // int8 [3072][2048]
#define WS_WGQ     6352896      // int8 [8192][2048]
#define WS_WUQ     23130112     // int8 [8192][2048]
#define WS_H       39907328     // fp16 [3072][8192]
#define WS_NEED    90238976
#define WS_ZERO_BYTES 49152     // sums + pooled + tsum

// ---------------- K1: abs-sum reduce for all 3 weight matrices ----------------
// 256 blocks/matrix -> only 256 atomics per slot, slots on separate cachelines.
// 64 float4 iters/thread, unroll 4 -> deep MLP.
__global__ __launch_bounds__(256) void abssum3_kernel(const float* __restrict__ Wg,
                                                      const float* __restrict__ Wu,
                                                      const float* __restrict__ Wd,
                                                      float* __restrict__ sums) {
  const float* w = (blockIdx.y == 0) ? Wg : (blockIdx.y == 1) ? Wu : Wd;
  const float4* w4 = (const float4*)w;
  const unsigned idx = blockIdx.x * 256 + threadIdx.x;    // 0..65535
  float s0 = 0.f, s1 = 0.f, s2 = 0.f, s3 = 0.f;
#pragma unroll 4
  for (int it = 0; it < 64; it += 4) {
    float4 a = w4[idx + (size_t)(it + 0) * 65536];
    float4 b = w4[idx + (size_t)(it + 1) * 65536];
    float4 c = w4[idx + (size_t)(it + 2) * 65536];
    float4 d = w4[idx + (size_t)(it + 3) * 65536];
    s0 += fabsf(a.x) + fabsf(a.y) + fabsf(a.z) + fabsf(a.w);
    s1 += fabsf(b.x) + fabsf(b.y) + fabsf(b.z) + fabsf(b.w);
    s2 += fabsf(c.x) + fabsf(c.y) + fabsf(c.z) + fabsf(c.w);
    s3 += fabsf(d.x) + fabsf(d.y) + fabsf(d.z) + fabsf(d.w);
  }
  float s = (s0 + s1) + (s2 + s3);
  for (int off = 32; off > 0; off >>= 1) s += __shfl_xor(s, off);
  __shared__ float wsum[4];
  int wave = threadIdx.x >> 6, lane = threadIdx.x & 63;
  if (lane == 0) wsum[wave] = s;
  __syncthreads();
  if (threadIdx.x == 0)
    atomicAdd(&sums[blockIdx.y * 64], (wsum[0] + wsum[1]) + (wsum[2] + wsum[3]));
}

// ---------------- K2: per-token absmax + int8 quantize of x ----------------
__global__ __launch_bounds__(256) void quant_x_kernel(const float* __restrict__ x,
                                                      int8_t* __restrict__ xq,
                                                      float* __restrict__ inv_sa) {
  const int tok = blockIdx.x, t = threadIdx.x;
  const float* row = x + (size_t)tok * DD;
  float4 v0 = *(const float4*)(row + t * 4);
  float4 v1 = *(const float4*)(row + 1024 + t * 4);
  float mx = fmaxf(fmaxf(fmaxf(fabsf(v0.x), fabsf(v0.y)), fmaxf(fabsf(v0.z), fabsf(v0.w))),
                   fmaxf(fmaxf(fabsf(v1.x), fabsf(v1.y)), fmaxf(fabsf(v1.z), fabsf(v1.w))));
  for (int off = 32; off > 0; off >>= 1) mx = fmaxf(mx, __shfl_xor(mx, off));
  __shared__ float wm[4];
  int wave = t >> 6, lane = t & 63;
  if (lane == 0) wm[wave] = mx;
  __syncthreads();
  float m = fmaxf(fmaxf(wm[0], wm[1]), fmaxf(wm[2], wm[3]));
  float mclip = fmaxf(m, 1e-5f);
  float sa = 127.0f / mclip;
  if (t == 0) inv_sa[tok] = mclip * (1.0f / 127.0f);
  float qv[8] = {v0.x, v0.y, v0.z, v0.w, v1.x, v1.y, v1.z, v1.w};
  unsigned p0 = 0, p1 = 0;
#pragma unroll
  for (int j = 0; j < 4; ++j) {
    int qi = (int)fminf(fmaxf(rintf(qv[j] * sa), -128.f), 127.f);
    p0 |= ((unsigned)(qi & 0xff)) << (8 * j);
  }
#pragma unroll
  for (int j = 0; j < 4; ++j) {
    int qi = (int)fminf(fmaxf(rintf(qv[4 + j] * sa), -128.f), 127.f);
    p1 |= ((unsigned)(qi & 0xff)) << (8 * j);
  }
  *(unsigned*)(xq + (size_t)tok * DD + t * 4) = p0;
  *(unsigned*)(xq + (size_t)tok * DD + 1024 + t * 4) = p1;
}

// ---------------- K3: ternarize Wg and Wu (grid.y selects), 16 floats/thread ----------------
__global__ __launch_bounds__(256) void quant_gu_kernel(const float* __restrict__ Wg,
                                                       const float* __restrict__ Wu,
                                                       int8_t* __restrict__ wgq,
                                                       int8_t* __restrict__ wuq,
                                                       const float* __restrict__ sums) {
  const int mat = blockIdx.y;
  const float* w = mat ? Wu : Wg;
  int8_t* wq = mat ? wuq : wgq;
  const float scale = 1.0f / fmaxf(sums[mat * 64] * INV_NW, 1e-5f);
  const unsigned base = blockIdx.x * 4096;   // floats per block
  float4 v[4];
#pragma unroll
  for (int j = 0; j < 4; ++j)
    v[j] = *(const float4*)(w + base + j * 1024 + threadIdx.x * 4);
#pragma unroll
  for (int j = 0; j < 4; ++j) {
    float vv[4] = {v[j].x, v[j].y, v[j].z, v[j].w};
    unsigned p = 0;
#pragma unroll
    for (int jj = 0; jj < 4; ++jj) {
      int qi = (int)fminf(fmaxf(rintf(vv[jj] * scale), -1.f), 1.f);
      p |= ((unsigned)(qi & 0xff)) << (8 * jj);
    }
    *(unsigned*)(wq + base + j * 1024 + threadIdx.x * 4) = p;
  }
}

// ---------------- K4: column-sum of ternary Wd -> tsum[FF] ----------------
__global__ __launch_bounds__(256) void wd_colsum_kernel(const float* __restrict__ wd,
                                                        const float* __restrict__ sums,
                                                        float* __restrict__ tsum) {
  const float scale = 1.0f / fmaxf(sums[128] * INV_NW, 1e-5f);
  const int k = blockIdx.x * 256 + threadIdx.x;   // 0..8191
  float acc = 0.f;
  const int d0 = blockIdx.y * 128;
  for (int d = d0; d < d0 + 128; ++d) {
    float w = wd[(size_t)d * FF + k];
    acc += fminf(fmaxf(rintf(w * scale), -1.f), 1.f);
  }
  atomicAdd(&tsum[k], acc);
}

// ---------------- K5: fused int8-MFMA GEMM (g and u) + silu*u -> fp16 h ----------------
__device__ __forceinline__ void gl_lds16(const void* g, void* l) {
  __builtin_amdgcn_global_load_lds((const __attribute__((address_space(1))) void*)g,
                                   (__attribute__((address_space(3))) void*)l, 16, 0, 0);
}

__global__ __launch_bounds__(256, 3) void gemm_gu_kernel(
    const int8_t* __restrict__ Aq,    // [3072][2048]
    const int8_t* __restrict__ Bgq,   // [8192][2048]
    const int8_t* __restrict__ Buq,   // [8192][2048]
    const float* __restrict__ inv_sa, // [3072]
    const float* __restrict__ sums,
    _Float16* __restrict__ Hbuf)      // [3072][8192]
{
  __shared__ int8_t ldsA[128 * 128];  // 16 KB, rows of 128 B = 8 chunks of 16 B
  __shared__ int8_t ldsG[64 * 128];   // 8 KB
  __shared__ int8_t ldsU[64 * 128];   // 8 KB

  const int t = threadIdx.x;
  const int wave = t >> 6, lane = t & 63;
  const int q = lane >> 4, ln = lane & 15;
  const int m0 = blockIdx.x * 128;    // token tile
  const int n0 = blockIdx.y * 64;     // F tile
  const int wm = (wave >> 1) * 64, wn = (wave & 1) * 32;

  i32x4 accg[4][2], accu[4][2];
#pragma unroll
  for (int i = 0; i < 4; ++i)
#pragma unroll
    for (int j = 0; j < 2; ++j) { accg[i][j] = i32x4{0,0,0,0}; accu[i][j] = i32x4{0,0,0,0}; }

  const int srow = lane >> 3;  // 0..7: row within an 8-row staging call
  const int sp = lane & 7;     // chunk position 0..7

  for (int k0 = 0; k0 < DD; k0 += 128) {
    __syncthreads();
#pragma unroll
    for (int j = 0; j < 4; ++j) {
      const int rl = wave * 32 + j * 8 + srow;
      const int cg = sp ^ (rl & 7);           // XOR swizzle over 8 chunk slots
      gl_lds16(Aq + (size_t)(m0 + rl) * DD + k0 + cg * 16,
               ldsA + (wave * 32 + j * 8) * 128);
    }
#pragma unroll
    for (int j = 0; j < 2; ++j) {
      const int rl = wave * 16 + j * 8 + srow;
      const int cg = sp ^ (rl & 7);
      gl_lds16(Bgq + (size_t)(n0 + rl) * DD + k0 + cg * 16,
               ldsG + (wave * 16 + j * 8) * 128);
      gl_lds16(Buq + (size_t)(n0 + rl) * DD + k0 + cg * 16,
               ldsU + (wave * 16 + j * 8) * 128);
    }
    __syncthreads();

#pragma unroll
    for (int s = 0; s < 2; ++s) {
      i32x4 af[4], gf[2], uf[2];
#pragma unroll
      for (int mt = 0; mt < 4; ++mt) {
        const int row = wm + mt * 16 + ln;
        const int p = (s * 4 + q) ^ (row & 7);
        af[mt] = *(const i32x4*)(ldsA + row * 128 + p * 16);
      }
#pragma unroll
      for (int nt = 0; nt < 2; ++nt) {
        const int row = wn + nt * 16 + ln;
        const int p = (s * 4 + q) ^ (row & 7);
        gf[nt] = *(const i32x4*)(ldsG + row * 128 + p * 16);
        uf[nt] = *(const i32x4*)(ldsU + row * 128 + p * 16);
      }
#pragma unroll
      for (int mt = 0; mt < 4; ++mt)
#pragma unroll
        for (int nt = 0; nt < 2; ++nt) {
          accg[mt][nt] = __builtin_amdgcn_mfma_i32_16x16x64_i8(af[mt], gf[nt], accg[mt][nt], 0, 0, 0);
          accu[mt][nt] = __builtin_amdgcn_mfma_i32_16x16x64_i8(af[mt], uf[nt], accu[mt][nt], 0, 0, 0);
        }
    }
  }

  const float meanWg = fmaxf(sums[0] * INV_NW, 1e-5f);
  const float meanWu = fmaxf(sums[64] * INV_NW, 1e-5f);
#pragma unroll
  for (int mt = 0; mt < 4; ++mt) {
#pragma unroll
    for (int r = 0; r < 4; ++r) {
      const int row = m0 + wm + mt * 16 + q * 4 + r;   // C/D layout: row = quad*4+reg
      const float isa = inv_sa[row];
      const float sg = isa * meanWg, su = isa * meanWu;
      _Float16* hrow = Hbuf + (size_t)row * FF + n0 + wn;
#pragma unroll
      for (int nt = 0; nt < 2; ++nt) {
        const float g = (float)accg[mt][nt][r] * sg;
        const float u = (float)accu[mt][nt][r] * su;
        const float sv = g / (1.0f + expf(-g));        // silu
        hrow[nt * 16 + ln] = (_Float16)(sv * u);       // col = lane&15
      }
    }
  }
}

// ---------------- K6: rmsnorm stats + requant + dot(tsum) per token (no atomics) ----------------
__global__ __launch_bounds__(256) void rms_quant_dot_kernel(
    const _Float16* __restrict__ H, const float* __restrict__ lnw,
    const float* __restrict__ tsum, float* __restrict__ pooled) {
  const int tok = blockIdx.x, t = threadIdx.x;
  const _Float16* row = H + (size_t)tok * FF;
  f16x8 hv[4];
  float4 lw[8];
  float ssq = 0.f, mx = 0.f;
#pragma unroll
  for (int i = 0; i < 4; ++i) {
    hv[i] = *(const f16x8*)(row + i * 2048 + t * 8);
    lw[2 * i] = *(const float4*)(lnw + i * 2048 + t * 8);
    lw[2 * i + 1] = *(const float4*)(lnw + i * 2048 + t * 8 + 4);
#pragma unroll
    for (int j = 0; j < 8; ++j) {
      float h = (float)hv[i][j];
      float w = (j < 4) ? ((const float*)&lw[2 * i])[j] : ((const float*)&lw[2 * i + 1])[j - 4];
      ssq += h * h;
      mx = fmaxf(mx, fabsf(h * w));
    }
  }
  for (int off = 32; off > 0; off >>= 1) {
    ssq += __shfl_xor(ssq, off);
    mx = fmaxf(mx, __shfl_xor(mx, off));
  }
  __shared__ float rs[4], rm[4], ra[4];
  const int wave = t >> 6, lane = t & 63;
  if (lane == 0) { rs[wave] = ssq; rm[wave] = mx; }
  __syncthreads();
  const float S = (rs[0] + rs[1]) + (rs[2] + rs[3]);
  const float M = fmaxf(fmaxf(rm[0], rm[1]), fmaxf(rm[2], rm[3]));
  const float r = rsqrtf(S * (1.0f / (float)FF) + 1e-6f);
  const float mc = fmaxf(M * r, 1e-5f);     // clip(max|y|, Q_EPS)
  const float as2 = 127.0f / mc;
  float acc = 0.f;
#pragma unroll
  for (int i = 0; i < 4; ++i) {
    float4 t0 = *(const float4*)(tsum + i * 2048 + t * 8);
    float4 t1 = *(const float4*)(tsum + i * 2048 + t * 8 + 4);
    const float* tw = (const float*)&t0;
    const float* lwp = (const float*)&lw[2 * i];
#pragma unroll
    for (int j = 0; j < 8; ++j) {
      float ts = (j < 4) ? tw[j] : ((const float*)&t1)[j - 4];
      float w = lwp[j];   // lw[2i] and lw[2i+1] are contiguous
      float y = (float)hv[i][j] * w * r;
      acc += fminf(fmaxf(rintf(y * as2), -128.f), 127.f) * ts;
    }
  }
  for (int off = 32; off > 0; off >>= 1) acc += __shfl_xor(acc, off);
  if (lane == 0) ra[wave] = acc;
  __syncthreads();
  if (t == 0)
    pooled[tok] = ((ra[0] + ra[1]) + (ra[2] + ra[3])) * (mc * (1.0f / 127.0f));
}

// ---------------- K7: classifier (reduces 128 tokens per (b,c) itself) ----------------
__global__ __launch_bounds__(256) void classifier_kernel(
    const float* __restrict__ pooled, const float* __restrict__ sums,
    const float* __restrict__ clsW, const float* __restrict__ clsb,
    float* __restrict__ out) {
  const int b = blockIdx.x, t = threadIdx.x;
  const float meanWd = fmaxf(sums[128] * INV_NW, 1e-5f);
  const float sc = meanWd * (1.0f / (float)(HH * DD));
  __shared__ float ps[3];
#pragma unroll
  for (int c = 0; c < 3; ++c) {
    float s = 0.f;
    if (t < 64) {
      const float* base = pooled + (b * 3 + c) * 128;
      s = base[t] + base[t + 64];
    }
    if (t < 64) {
      for (int off = 32; off > 0; off >>= 1) s += __shfl_xor(s, off);
      if (t == 0) ps[c] = s * sc;
    }
    __syncthreads();
  }
  const float p0 = ps[0], p1 = ps[1], p2 = ps[2];
  for (int n = t; n < NCLS; n += 256)
    out[b * NCLS + n] = clsb[n] + p0 * clsW[n * 3 + 0] + p1 * clsW[n * 3 + 1] + p2 * clsW[n * 3 + 2];
}

// ---------------- launch ----------------
extern "C" void kernel_launch(void* const* d_in, const int* in_sizes, int n_in,
                              void* d_out, int out_size, void* d_ws, size_t ws_size,
                              hipStream_t stream) {
  if (n_in < 7 || ws_size < (size_t)WS_NEED) return;
  const float* x = (const float*)d_in[0];
  const float* Wg = (const float*)d_in[1];
  const float* Wu = (const float*)d_in[2];
  const float* Wd = (const float*)d_in[3];
  const float* lnw = (const float*)d_in[4];
  const float* clsW = (const float*)d_in[5];
  const float* clsb = (const float*)d_in[6];
  float* out = (float*)d_out;
  char* ws = (char*)d_ws;
  float* sums = (float*)(ws + WS_SUMS);
  float* pooled = (float*)(ws + WS_POOLED);
  float* tsum = (float*)(ws + WS_TSUM);
  float* inv_sa = (float*)(ws + WS_INVSA);
  int8_t* xq = (int8_t*)(ws + WS_XQ);
  int8_t* wgq = (int8_t*)(ws + WS_WGQ);
  int8_t* wuq = (int8_t*)(ws + WS_WUQ);
  _Float16* hbuf = (_Float16*)(ws + WS_H);

  hipMemsetAsync(ws, 0, WS_ZERO_BYTES, stream);
  abssum3_kernel<<<dim3(256, 3), 256, 0, stream>>>(Wg, Wu, Wd, sums);
  quant_x_kernel<<<MTOK, 256, 0, stream>>>(x, xq, inv_sa);
  quant_gu_kernel<<<dim3(4096, 2), 256, 0, stream>>>(Wg, Wu, wgq, wuq, sums);
  wd_colsum_kernel<<<dim3(32, 16), 256, 0, stream>>>(Wd, sums, tsum);
  gemm_gu_kernel<<<dim3(24, 128), 256, 0, stream>>>(xq, wgq, wuq, inv_sa, sums, hbuf);
  rms_quant_dot_kernel<<<MTOK, 256, 0, stream>>>(hbuf, lnw, tsum, pooled);
  classifier_kernel<<<BB, 256, 0, stream>>>(pooled, sums, clsW, clsb, out);
  (void)in_sizes; (void)out_size;
}